// Round 13
// baseline (853.535 us; speedup 1.0000x reference)
//
#include <hip/hip_runtime.h>

typedef unsigned long long u64;
typedef unsigned int u32;

#define G_ 32
#define L_ 16384
#define D_ 128
#define ONEHOT_ 33554432LL

// async 16B/lane global->LDS (lds base wave-uniform; HW adds lane*16)
__device__ inline void gload16(const float* g, float* lds) {
  __builtin_amdgcn_global_load_lds(
      (const __attribute__((address_space(1))) unsigned int*)g,
      (__attribute__((address_space(3))) unsigned int*)lds, 16, 0, 0);
}

// issue quarter nq (linear index tile*4+q) into per-wave dbuf slot nq&1.
// LDS f4 layout: idx = p*8 + (d4 ^ ((p>>2)<<1))  [source-side swizzle so the
// 4 pg broadcast-read groups hit disjoint bank quads; gload dest stays linear]
__device__ inline void issue_stage(const float* xg, float4* xw, int wbase,
                                   int nq, int lane) {
  int tb = wbase + ((nq >> 2) << 4);
  int qq = nq & 3;
  float4* dst = xw + ((nq & 1) << 7);
  #pragma unroll
  for (int k = 0; k < 2; ++k) {
    int idx = (k << 6) + lane;
    int p = idx >> 3, d4s = idx & 7;
    int d4 = d4s ^ ((p >> 2) << 1);
    const float* src = xg + ((size_t)(tb + p) << 7) + (qq << 5) + (d4 << 2);
    gload16(src, (float*)(dst + (k << 6)));
  }
}

// ---------------------------------------------------------------------------
// k1: per-window sums -> normalized init codebook c0n [g][w][d]. (R1 verbatim)
// ---------------------------------------------------------------------------
__global__ __launch_bounds__(256) void k1_sums(const float* __restrict__ x,
                                               float* __restrict__ c0n) {
  int blk = blockIdx.x;              // g*64 + w
  const float* xp = x + ((size_t)blk << 15);
  int t = threadIdx.x;
  int d4 = t & 31, r0 = t >> 5;
  float4 acc = make_float4(0.f, 0.f, 0.f, 0.f);
  #pragma unroll 4
  for (int r = r0; r < 256; r += 8) {
    float4 v = *(const float4*)(xp + r * D_ + d4 * 4);
    acc.x += v.x; acc.y += v.y; acc.z += v.z; acc.w += v.w;
  }
  __shared__ float4 part[8][32];
  __shared__ double ssq[33];
  part[r0][d4] = acc;
  __syncthreads();
  if (t < 32) {
    float4 s = part[0][t];
    for (int r = 1; r < 8; ++r) {
      float4 v = part[r][t];
      s.x += v.x; s.y += v.y; s.z += v.z; s.w += v.w;
    }
    part[0][t] = s;
    ssq[t] = (double)s.x * s.x + (double)s.y * s.y + (double)s.z * s.z + (double)s.w * s.w;
  }
  __syncthreads();
  if (t == 0) {
    double tot = 0.0;
    for (int i = 0; i < 32; ++i) tot += ssq[i];
    ssq[32] = 1.0 / sqrt(tot);
  }
  __syncthreads();
  if (t < 32) {
    float rn = (float)ssq[32];
    float4 s = part[0][t];
    float4 c = make_float4(s.x * rn, s.y * rn, s.z * rn, s.w * rn);
    *(float4*)(c0n + ((size_t)blk << 7) + t * 4) = c;
  }
}

// ---------------------------------------------------------------------------
// k2: register-blocked affinity (R11 numerics verbatim) with async staging:
// global_load_lds (zero VGPR cost -> no spill, unlike R12's reg prefetch),
// per-wave double-buffered quarters, counted s_waitcnt vmcnt(2) so the next
// quarter's DMA stays in flight under the current quarter's 512-FMA block.
// ---------------------------------------------------------------------------
__global__ __launch_bounds__(512)
void k2_assign(const float* __restrict__ x,
               const float* __restrict__ c0n,
               u32* __restrict__ aPack,
               u64* __restrict__ best) {
  __shared__ float4 cL[64 * 33];      // 33792 B
  __shared__ float4 xq[8][256];       // 32768 B: per-wave 2 x (16 pts x 8 f4)
  int g = blockIdx.x >> 4, bsub = blockIdx.x & 15;
  int t = threadIdx.x, lane = t & 63, wv = t >> 6;
  int l15 = lane & 15, pg = lane >> 4;
  const float* xg = x + ((size_t)g << 21);
  const float4* cg4 = (const float4*)(c0n + ((size_t)g << 13));
  for (int i = t; i < 2048; i += 512)
    cL[(i >> 5) * 33 + (i & 31)] = cg4[i];
  __syncthreads();

  float4* xw = xq[wv];

  float rbv[4]; int rbp[4];
  #pragma unroll
  for (int s = 0; s < 4; ++s) { rbv[s] = -3.0e38f; rbp[s] = 0; }

  int wbase = bsub * 1024 + wv * 128;
  issue_stage(xg, xw, wbase, 0, lane);

  for (int tile = 0; tile < 8; ++tile) {
    int p0 = wbase + tile * 16;
    float4 acc[4][4];
    #pragma unroll
    for (int s = 0; s < 4; ++s)
      #pragma unroll
      for (int j = 0; j < 4; ++j) acc[s][j] = make_float4(0.f, 0.f, 0.f, 0.f);

    for (int q = 0; q < 4; ++q) {
      int qi = (tile << 2) + q;
      if (qi < 31) {
        issue_stage(xg, xw, wbase, qi + 1, lane);
        asm volatile("s_waitcnt vmcnt(2)" ::: "memory");  // current quarter landed
      } else {
        asm volatile("s_waitcnt vmcnt(0)" ::: "memory");
      }
      const float4* xb = xw + ((q & 1) << 7);
      #pragma unroll
      for (int d4l = 0; d4l < 8; ++d4l) {
        float4 ca[4];
        #pragma unroll
        for (int s = 0; s < 4; ++s)
          ca[s] = cL[(l15 + (s << 4)) * 33 + (q << 3) + d4l];
        #pragma unroll
        for (int j = 0; j < 4; ++j) {
          float4 xv = xb[((pg << 2) + j) * 8 + (d4l ^ (pg << 1))];
          #pragma unroll
          for (int s = 0; s < 4; ++s) {
            acc[s][j].x += ca[s].x * xv.x;
            acc[s][j].y += ca[s].y * xv.y;
            acc[s][j].z += ca[s].z * xv.z;
            acc[s][j].w += ca[s].w * xv.w;
          }
        }
      }
    }

    int w1s[4];
    #pragma unroll
    for (int j = 0; j < 4; ++j) {
      int p = p0 + pg * 4 + j;
      float av[4];
      #pragma unroll
      for (int s = 0; s < 4; ++s)
        av[s] = (acc[s][j].x + acc[s][j].y) + (acc[s][j].z + acc[s][j].w);
      // per-window running best (strict >, points ascend -> min-p ties)
      #pragma unroll
      for (int s = 0; s < 4; ++s)
        if (av[s] > rbv[s]) { rbv[s] = av[s]; rbp[s] = p; }
      // per-point argmax over 64 windows (min-w ties, numpy semantics)
      float v1 = av[0]; int w1 = l15;
      #pragma unroll
      for (int s = 1; s < 4; ++s)
        if (av[s] > v1) { v1 = av[s]; w1 = l15 + (s << 4); }
      #pragma unroll
      for (int off = 1; off <= 8; off <<= 1) {
        float ov = __shfl_xor(v1, off); int ow = __shfl_xor(w1, off);
        if (ov > v1 || (ov == v1 && ow < w1)) { v1 = ov; w1 = ow; }
      }
      w1s[j] = w1;                   // identical across the 16 lanes of pg grp
    }

    // packed assignment write: pg's l15==0 lane packs its 4 points into 1 u32
    if (l15 == 0) {
      u32 pk4 = (u32)w1s[0] | ((u32)w1s[1] << 8) |
                ((u32)w1s[2] << 16) | ((u32)w1s[3] << 24);
      aPack[((g * L_ + p0) >> 2) + pg] = pk4;
    }
  }

  // merge per-window best across the 4 pg groups, then global atomicMax
  #pragma unroll
  for (int s = 0; s < 4; ++s) {
    #pragma unroll
    for (int off = 16; off <= 32; off <<= 1) {
      float ov = __shfl_xor(rbv[s], off); int op = __shfl_xor(rbp[s], off);
      if (ov > rbv[s] || (ov == rbv[s] && op < rbp[s])) { rbv[s] = ov; rbp[s] = op; }
    }
  }
  if (pg == 0) {
    #pragma unroll
    for (int s = 0; s < 4; ++s) {
      u32 key = __float_as_uint(rbv[s]);
      key ^= (key & 0x80000000u) ? 0xFFFFFFFFu : 0x80000000u;
      u64 pk = ((u64)key << 32) | (u64)(0xFFFFFFFFu - (u32)rbp[s]);
      atomicMax(&best[(g << 6) + l15 + (s << 4)], pk);
    }
  }
}

// ---------------------------------------------------------------------------
// k2d: deterministic delta accumulation (R11 verbatim). i64 fixed-point LDS
// atomics (exact, associative), flushed with global u64 atomics.
// ---------------------------------------------------------------------------
__global__ __launch_bounds__(512)
void k2d_delta(const float* __restrict__ x,
               const u32* __restrict__ aPack,
               u64* __restrict__ deltaI) {
  __shared__ u64 ldsD[64 * 130];      // 66560 B
  int g = blockIdx.x >> 4, bsub = blockIdx.x & 15;
  int t = threadIdx.x, lane = t & 63, wv = t >> 6;
  const float* xg = x + ((size_t)g << 21);
  for (int i = t; i < 64 * 130; i += 512) ldsD[i] = 0ULL;
  __syncthreads();

  int pbase = bsub * 1024 + wv * 128;
  #pragma unroll 4
  for (int i = 0; i < 128; ++i) {
    int p = pbase + i;
    u32 pk4 = aPack[(g * L_ + p) >> 2];
    int aw = (int)((pk4 >> ((p & 3) * 8)) & 63u);
    const float* xr = xg + ((size_t)p << 7);
    float va = xr[lane];
    float vb = xr[lane + 64];
    u64* dst = ldsD + aw * 130 + lane;
    atomicAdd(dst, (u64)(long long)__double2ll_rn((double)va * 4294967296.0));
    atomicAdd(dst + 64, (u64)(long long)__double2ll_rn((double)vb * 4294967296.0));
  }

  __syncthreads();
  for (int i = t; i < 8192; i += 512) {
    u64 v = ldsD[(i >> 7) * 130 + (i & 127)];
    if (v) atomicAdd(&deltaI[((size_t)g << 13) + i], v);
  }
}

// ---------------------------------------------------------------------------
// k3: finalize codebook (R1 verbatim); writes cOut (d_out tail) + c2n (ws).
// ---------------------------------------------------------------------------
__global__ __launch_bounds__(128) void k3_final(const float* __restrict__ x,
                                                const float* __restrict__ c0n,
                                                const u64* __restrict__ deltaI,
                                                const u64* __restrict__ best,
                                                float* __restrict__ cOut,
                                                float* __restrict__ c2n) {
  int blk = blockIdx.x, g = blk >> 6;
  int d = threadIdx.x;
  u64 pk = best[blk];
  int bl = (int)(0xFFFFFFFFu - (u32)(pk & 0xFFFFFFFFull));
  float xb = x[((size_t)g << 21) + ((size_t)bl << 7) + d];
  long long di = (long long)deltaI[((size_t)blk << 7) + d];
  double delta = (double)di * (1.0 / 4294967296.0) + (double)xb;

  __shared__ double red[128];
  __shared__ double inv;
  red[d] = delta * delta;
  __syncthreads();
  for (int s = 64; s > 0; s >>= 1) {
    if (d < s) red[d] += red[d + s];
    __syncthreads();
  }
  if (d == 0) inv = 1.0 / sqrt(red[0]);
  __syncthreads();
  float dn = (float)(delta * inv);
  float b2 = 0.5f * c0n[((size_t)blk << 7) + d] + 0.5f * dn;
  __syncthreads();
  red[d] = (double)b2 * b2;
  __syncthreads();
  for (int s = 64; s > 0; s >>= 1) {
    if (d < s) red[d] += red[d + s];
    __syncthreads();
  }
  if (d == 0) inv = 1.0 / sqrt(red[0]);
  __syncthreads();
  float cf = b2 * (float)inv;
  cOut[((size_t)blk << 7) + d] = cf;
  c2n[((size_t)blk << 7) + d] = cf;
}

// ---------------------------------------------------------------------------
// k4: final cos_sim, same async double-buffered staging as k2. Numerics
// identical to R8/R11. LDS 66.5 KB; grid 512; 2 blocks/CU; 4 waves/SIMD.
// ---------------------------------------------------------------------------
__global__ __launch_bounds__(512)
void k4_onehot(const float* __restrict__ x,
               const float* __restrict__ c2n,
               float* __restrict__ out) {
  __shared__ float4 cL[64 * 33];
  __shared__ float4 xq[8][256];
  int g = blockIdx.x >> 4, bsub = blockIdx.x & 15;
  int t = threadIdx.x, lane = t & 63, wv = t >> 6;
  int l15 = lane & 15, pg = lane >> 4;
  const float* xg = x + ((size_t)g << 21);
  const float4* cg4 = (const float4*)(c2n + ((size_t)g << 13));
  for (int i = t; i < 2048; i += 512)
    cL[(i >> 5) * 33 + (i & 31)] = cg4[i];
  __syncthreads();

  float4* xw = xq[wv];
  int wbase = bsub * 1024 + wv * 128;
  issue_stage(xg, xw, wbase, 0, lane);

  for (int tile = 0; tile < 8; ++tile) {
    int p0 = wbase + tile * 16;
    float4 acc[4][4];
    #pragma unroll
    for (int s = 0; s < 4; ++s)
      #pragma unroll
      for (int j = 0; j < 4; ++j) acc[s][j] = make_float4(0.f, 0.f, 0.f, 0.f);

    for (int q = 0; q < 4; ++q) {
      int qi = (tile << 2) + q;
      if (qi < 31) {
        issue_stage(xg, xw, wbase, qi + 1, lane);
        asm volatile("s_waitcnt vmcnt(2)" ::: "memory");
      } else {
        asm volatile("s_waitcnt vmcnt(0)" ::: "memory");
      }
      const float4* xb = xw + ((q & 1) << 7);
      #pragma unroll
      for (int d4l = 0; d4l < 8; ++d4l) {
        float4 ca[4];
        #pragma unroll
        for (int s = 0; s < 4; ++s)
          ca[s] = cL[(l15 + (s << 4)) * 33 + (q << 3) + d4l];
        #pragma unroll
        for (int j = 0; j < 4; ++j) {
          float4 xv = xb[((pg << 2) + j) * 8 + (d4l ^ (pg << 1))];
          #pragma unroll
          for (int s = 0; s < 4; ++s) {
            acc[s][j].x += ca[s].x * xv.x;
            acc[s][j].y += ca[s].y * xv.y;
            acc[s][j].z += ca[s].z * xv.z;
            acc[s][j].w += ca[s].w * xv.w;
          }
        }
      }
    }

    #pragma unroll
    for (int j = 0; j < 4; ++j) {
      int p = p0 + pg * 4 + j;
      float av[4];
      #pragma unroll
      for (int s = 0; s < 4; ++s)
        av[s] = (acc[s][j].x + acc[s][j].y) + (acc[s][j].z + acc[s][j].w);
      float v1 = av[0]; int w1 = l15;
      #pragma unroll
      for (int s = 1; s < 4; ++s)
        if (av[s] > v1) { v1 = av[s]; w1 = l15 + (s << 4); }
      #pragma unroll
      for (int off = 1; off <= 8; off <<= 1) {
        float ov = __shfl_xor(v1, off); int ow = __shfl_xor(w1, off);
        if (ov > v1 || (ov == v1 && ow < w1)) { v1 = ov; w1 = ow; }
      }
      // one-hot row p: lane l15 owns cols 4*l15..+3 (64 lanes -> 1KB store)
      int w0 = l15 << 2;
      float4 vv;
      vv.x = (w1 == w0    ) ? 1.f : 0.f;
      vv.y = (w1 == w0 + 1) ? 1.f : 0.f;
      vv.z = (w1 == w0 + 2) ? 1.f : 0.f;
      vv.w = (w1 == w0 + 3) ? 1.f : 0.f;
      *(float4*)(out + (((size_t)(g * L_ + p)) << 6) + w0) = vv;
    }
  }
}

extern "C" void kernel_launch(void* const* d_in, const int* in_sizes, int n_in,
                              void* d_out, int out_size, void* d_ws, size_t ws_size,
                              hipStream_t stream) {
  const float* x = (const float*)d_in[0];
  float* out = (float*)d_out;
  float* cOut = out + ONEHOT_;
  char* ws = (char*)d_ws;
  float* c0n   = (float*)(ws);                     // 1 MiB [g][w][d]
  float* c2n   = (float*)(ws + (1u << 20));        // 1 MiB [g][w][d] final
  u64*  deltaI = (u64*)(ws + (3u << 20));          // 2 MiB [g][w][d] i64 fixed-point
  u64*  best   = (u64*)(ws + (5u << 20));          // 16 KiB [g][w] packed key||~p
  u32*  aPack  = (u32*)(ws + (5u << 20) + 65536);  // 512 KiB packed assignments

  // zero delta accumulators + best (0 == -inf sentinel under the key transform)
  hipMemsetAsync(ws + (3u << 20), 0, (2u << 20) + 16384, stream);

  hipLaunchKernelGGL(k1_sums,   dim3(2048), dim3(256), 0, stream, x, c0n);
  hipLaunchKernelGGL(k2_assign, dim3(512),  dim3(512), 0, stream, x, c0n, aPack, best);
  hipLaunchKernelGGL(k2d_delta, dim3(512),  dim3(512), 0, stream, x, aPack, deltaI);
  hipLaunchKernelGGL(k3_final,  dim3(2048), dim3(128), 0, stream,
                     x, c0n, deltaI, best, cOut, c2n);
  hipLaunchKernelGGL(k4_onehot, dim3(512),  dim3(512), 0, stream, x, c2n, out);
}

// Round 14
// 485.284 us; speedup vs baseline: 1.7588x; 1.7588x over previous
//
#include <hip/hip_runtime.h>

typedef unsigned long long u64;
typedef unsigned int u32;

#define G_ 32
#define L_ 16384
#define D_ 128
#define ONEHOT_ 33554432LL

// ---------------------------------------------------------------------------
// k1: per-window sums -> normalized init codebook c0n [g][w][d]. (R1 verbatim)
// ---------------------------------------------------------------------------
__global__ __launch_bounds__(256) void k1_sums(const float* __restrict__ x,
                                               float* __restrict__ c0n) {
  int blk = blockIdx.x;              // g*64 + w
  const float* xp = x + ((size_t)blk << 15);
  int t = threadIdx.x;
  int d4 = t & 31, r0 = t >> 5;
  float4 acc = make_float4(0.f, 0.f, 0.f, 0.f);
  #pragma unroll 4
  for (int r = r0; r < 256; r += 8) {
    float4 v = *(const float4*)(xp + r * D_ + d4 * 4);
    acc.x += v.x; acc.y += v.y; acc.z += v.z; acc.w += v.w;
  }
  __shared__ float4 part[8][32];
  __shared__ double ssq[33];
  part[r0][d4] = acc;
  __syncthreads();
  if (t < 32) {
    float4 s = part[0][t];
    for (int r = 1; r < 8; ++r) {
      float4 v = part[r][t];
      s.x += v.x; s.y += v.y; s.z += v.z; s.w += v.w;
    }
    part[0][t] = s;
    ssq[t] = (double)s.x * s.x + (double)s.y * s.y + (double)s.z * s.z + (double)s.w * s.w;
  }
  __syncthreads();
  if (t == 0) {
    double tot = 0.0;
    for (int i = 0; i < 32; ++i) tot += ssq[i];
    ssq[32] = 1.0 / sqrt(tot);
  }
  __syncthreads();
  if (t < 32) {
    float rn = (float)ssq[32];
    float4 s = part[0][t];
    float4 c = make_float4(s.x * rn, s.y * rn, s.z * rn, s.w * rn);
    *(float4*)(c0n + ((size_t)blk << 7) + t * 4) = c;
  }
}

// ---------------------------------------------------------------------------
// k2: register-blocked affinity (R11 verbatim — verified pass, no spill).
// acc[4][4] = 64 VGPR acc at the 128-VGPR toolchain cap; LDS 52 KB ->
// 2 blocks/CU -> 4 waves/SIMD. Mixed DS+VALU-bound (~64 ds_read_b128 per
// 512 v_fmac per quarter) -> VALUBusy ~54-57% is this structure's ceiling.
// ---------------------------------------------------------------------------
__global__ __launch_bounds__(512)
void k2_assign(const float* __restrict__ x,
               const float* __restrict__ c0n,
               u32* __restrict__ aPack,
               u64* __restrict__ best) {
  __shared__ float4 cL[64 * 33];      // 33792 B
  __shared__ float4 xq[8][16 * 9];    // 18432 B (per-wave 16 pts x 8 f4, pad 9)
  int g = blockIdx.x >> 4, bsub = blockIdx.x & 15;
  int t = threadIdx.x, lane = t & 63, wv = t >> 6;
  int l15 = lane & 15, pg = lane >> 4;
  const float* xg = x + ((size_t)g << 21);
  const float4* cg4 = (const float4*)(c0n + ((size_t)g << 13));
  for (int i = t; i < 2048; i += 512)
    cL[(i >> 5) * 33 + (i & 31)] = cg4[i];
  __syncthreads();

  float4* xw = xq[wv];
  int sp = lane >> 2, sh = lane & 3;     // staging: 4 lanes per point

  float rbv[4]; int rbp[4];
  #pragma unroll
  for (int s = 0; s < 4; ++s) { rbv[s] = -3.0e38f; rbp[s] = 0; }

  int wbase = bsub * 1024 + wv * 128;
  for (int tile = 0; tile < 8; ++tile) {
    int p0 = wbase + tile * 16;
    float4 acc[4][4];
    #pragma unroll
    for (int s = 0; s < 4; ++s)
      #pragma unroll
      for (int j = 0; j < 4; ++j) acc[s][j] = make_float4(0.f, 0.f, 0.f, 0.f);

    for (int q = 0; q < 4; ++q) {
      // per-wave stage: 16 points x 8 float4 (dims q*32..q*32+31)
      const float4* gsrc = (const float4*)(xg + ((size_t)(p0 + sp) << 7) + (q << 5));
      float4* xrow = xw + sp * 9;
      xrow[sh * 2]     = gsrc[sh * 2];
      xrow[sh * 2 + 1] = gsrc[sh * 2 + 1];
      // no barrier: xq[wv] is wave-private; DS pipe is in-order per wave
      #pragma unroll
      for (int d4l = 0; d4l < 8; ++d4l) {
        float4 ca[4];
        #pragma unroll
        for (int s = 0; s < 4; ++s)
          ca[s] = cL[(l15 + (s << 4)) * 33 + (q << 3) + d4l];
        #pragma unroll
        for (int j = 0; j < 4; ++j) {
          float4 xv = xw[(pg * 4 + j) * 9 + d4l];
          #pragma unroll
          for (int s = 0; s < 4; ++s) {
            acc[s][j].x += ca[s].x * xv.x;
            acc[s][j].y += ca[s].y * xv.y;
            acc[s][j].z += ca[s].z * xv.z;
            acc[s][j].w += ca[s].w * xv.w;
          }
        }
      }
    }

    int w1s[4];
    #pragma unroll
    for (int j = 0; j < 4; ++j) {
      int p = p0 + pg * 4 + j;
      float av[4];
      #pragma unroll
      for (int s = 0; s < 4; ++s)
        av[s] = (acc[s][j].x + acc[s][j].y) + (acc[s][j].z + acc[s][j].w);
      // per-window running best (strict >, points ascend -> min-p ties)
      #pragma unroll
      for (int s = 0; s < 4; ++s)
        if (av[s] > rbv[s]) { rbv[s] = av[s]; rbp[s] = p; }
      // per-point argmax over 64 windows (min-w ties, numpy semantics)
      float v1 = av[0]; int w1 = l15;
      #pragma unroll
      for (int s = 1; s < 4; ++s)
        if (av[s] > v1) { v1 = av[s]; w1 = l15 + (s << 4); }
      #pragma unroll
      for (int off = 1; off <= 8; off <<= 1) {
        float ov = __shfl_xor(v1, off); int ow = __shfl_xor(w1, off);
        if (ov > v1 || (ov == v1 && ow < w1)) { v1 = ov; w1 = ow; }
      }
      w1s[j] = w1;                   // identical across the 16 lanes of pg grp
    }

    // packed assignment write: pg's l15==0 lane packs its 4 points into 1 u32
    if (l15 == 0) {
      u32 pk4 = (u32)w1s[0] | ((u32)w1s[1] << 8) |
                ((u32)w1s[2] << 16) | ((u32)w1s[3] << 24);
      aPack[((g * L_ + p0) >> 2) + pg] = pk4;
    }
  }

  // merge per-window best across the 4 pg groups, then global atomicMax
  #pragma unroll
  for (int s = 0; s < 4; ++s) {
    #pragma unroll
    for (int off = 16; off <= 32; off <<= 1) {
      float ov = __shfl_xor(rbv[s], off); int op = __shfl_xor(rbp[s], off);
      if (ov > rbv[s] || (ov == rbv[s] && op < rbp[s])) { rbv[s] = ov; rbp[s] = op; }
    }
  }
  if (pg == 0) {
    #pragma unroll
    for (int s = 0; s < 4; ++s) {
      u32 key = __float_as_uint(rbv[s]);
      key ^= (key & 0x80000000u) ? 0xFFFFFFFFu : 0x80000000u;
      u64 pk = ((u64)key << 32) | (u64)(0xFFFFFFFFu - (u32)rbp[s]);
      atomicMax(&best[(g << 6) + l15 + (s << 4)], pk);
    }
  }
}

// ---------------------------------------------------------------------------
// k2d: deterministic delta accumulation, retuned: 1024-thread blocks are safe
// HERE (register need << 64, so the toolchain's 64-VGPR allocation for
// 1024-thr blocks cannot spill) -> LDS 66.5 KB, 2 blocks/CU, 16 waves/block
// -> 8 waves/SIMD (2x R11's latency hiding for the load->atomic chains).
// pk4 cached once per 4 points (3/4 fewer aPack loads). i64 fixed-point LDS
// atomics are exact & associative -> deltaI bit-identical to R11/R8.
// ---------------------------------------------------------------------------
__global__ __launch_bounds__(1024)
void k2d_delta(const float* __restrict__ x,
               const u32* __restrict__ aPack,
               u64* __restrict__ deltaI) {
  __shared__ u64 ldsD[64 * 130];      // 66560 B
  int g = blockIdx.x >> 3, bsub = blockIdx.x & 7;
  int t = threadIdx.x, lane = t & 63, wv = t >> 6;
  const float* xg = x + ((size_t)g << 21);
  for (int i = t; i < 64 * 130; i += 1024) ldsD[i] = 0ULL;
  __syncthreads();

  int pbase = bsub * 2048 + wv * 128;      // 8 bsub x 16 waves x 128 pts
  #pragma unroll 2
  for (int i4 = 0; i4 < 32; ++i4) {
    int p0 = pbase + i4 * 4;
    u32 pk4 = aPack[(g * L_ + p0) >> 2];
    #pragma unroll
    for (int j = 0; j < 4; ++j) {
      int aw = (int)((pk4 >> (j * 8)) & 63u);
      const float* xr = xg + ((size_t)(p0 + j) << 7);
      float va = xr[lane];
      float vb = xr[lane + 64];
      u64* dst = ldsD + aw * 130 + lane;
      atomicAdd(dst, (u64)(long long)__double2ll_rn((double)va * 4294967296.0));
      atomicAdd(dst + 64, (u64)(long long)__double2ll_rn((double)vb * 4294967296.0));
    }
  }

  __syncthreads();
  for (int i = t; i < 8192; i += 1024) {
    u64 v = ldsD[(i >> 7) * 130 + (i & 127)];
    if (v) atomicAdd(&deltaI[((size_t)g << 13) + i], v);
  }
}

// ---------------------------------------------------------------------------
// k3: finalize codebook (R1 verbatim); writes cOut (d_out tail) + c2n (ws).
// ---------------------------------------------------------------------------
__global__ __launch_bounds__(128) void k3_final(const float* __restrict__ x,
                                                const float* __restrict__ c0n,
                                                const u64* __restrict__ deltaI,
                                                const u64* __restrict__ best,
                                                float* __restrict__ cOut,
                                                float* __restrict__ c2n) {
  int blk = blockIdx.x, g = blk >> 6;
  int d = threadIdx.x;
  u64 pk = best[blk];
  int bl = (int)(0xFFFFFFFFu - (u32)(pk & 0xFFFFFFFFull));
  float xb = x[((size_t)g << 21) + ((size_t)bl << 7) + d];
  long long di = (long long)deltaI[((size_t)blk << 7) + d];
  double delta = (double)di * (1.0 / 4294967296.0) + (double)xb;

  __shared__ double red[128];
  __shared__ double inv;
  red[d] = delta * delta;
  __syncthreads();
  for (int s = 64; s > 0; s >>= 1) {
    if (d < s) red[d] += red[d + s];
    __syncthreads();
  }
  if (d == 0) inv = 1.0 / sqrt(red[0]);
  __syncthreads();
  float dn = (float)(delta * inv);
  float b2 = 0.5f * c0n[((size_t)blk << 7) + d] + 0.5f * dn;
  __syncthreads();
  red[d] = (double)b2 * b2;
  __syncthreads();
  for (int s = 64; s > 0; s >>= 1) {
    if (d < s) red[d] += red[d + s];
    __syncthreads();
  }
  if (d == 0) inv = 1.0 / sqrt(red[0]);
  __syncthreads();
  float cf = b2 * (float)inv;
  cOut[((size_t)blk << 7) + d] = cf;
  c2n[((size_t)blk << 7) + d] = cf;
}

// ---------------------------------------------------------------------------
// k4: final cos_sim (R11 verbatim — verified pass). acc[4][4] tile, LDS 52 KB,
// 2 blocks/CU, 4 waves/SIMD; per-point argmax; coalesced float4 one-hot rows.
// ---------------------------------------------------------------------------
__global__ __launch_bounds__(512)
void k4_onehot(const float* __restrict__ x,
               const float* __restrict__ c2n,
               float* __restrict__ out) {
  __shared__ float4 cL[64 * 33];
  __shared__ float4 xq[8][16 * 9];
  int g = blockIdx.x >> 4, bsub = blockIdx.x & 15;
  int t = threadIdx.x, lane = t & 63, wv = t >> 6;
  int l15 = lane & 15, pg = lane >> 4;
  const float* xg = x + ((size_t)g << 21);
  const float4* cg4 = (const float4*)(c2n + ((size_t)g << 13));
  for (int i = t; i < 2048; i += 512)
    cL[(i >> 5) * 33 + (i & 31)] = cg4[i];
  __syncthreads();

  float4* xw = xq[wv];
  int sp = lane >> 2, sh = lane & 3;

  int wbase = bsub * 1024 + wv * 128;
  for (int tile = 0; tile < 8; ++tile) {
    int p0 = wbase + tile * 16;
    float4 acc[4][4];
    #pragma unroll
    for (int s = 0; s < 4; ++s)
      #pragma unroll
      for (int j = 0; j < 4; ++j) acc[s][j] = make_float4(0.f, 0.f, 0.f, 0.f);

    for (int q = 0; q < 4; ++q) {
      const float4* gsrc = (const float4*)(xg + ((size_t)(p0 + sp) << 7) + (q << 5));
      float4* xrow = xw + sp * 9;
      xrow[sh * 2]     = gsrc[sh * 2];
      xrow[sh * 2 + 1] = gsrc[sh * 2 + 1];
      #pragma unroll
      for (int d4l = 0; d4l < 8; ++d4l) {
        float4 ca[4];
        #pragma unroll
        for (int s = 0; s < 4; ++s)
          ca[s] = cL[(l15 + (s << 4)) * 33 + (q << 3) + d4l];
        #pragma unroll
        for (int j = 0; j < 4; ++j) {
          float4 xv = xw[(pg * 4 + j) * 9 + d4l];
          #pragma unroll
          for (int s = 0; s < 4; ++s) {
            acc[s][j].x += ca[s].x * xv.x;
            acc[s][j].y += ca[s].y * xv.y;
            acc[s][j].z += ca[s].z * xv.z;
            acc[s][j].w += ca[s].w * xv.w;
          }
        }
      }
    }

    #pragma unroll
    for (int j = 0; j < 4; ++j) {
      int p = p0 + pg * 4 + j;
      float av[4];
      #pragma unroll
      for (int s = 0; s < 4; ++s)
        av[s] = (acc[s][j].x + acc[s][j].y) + (acc[s][j].z + acc[s][j].w);
      float v1 = av[0]; int w1 = l15;
      #pragma unroll
      for (int s = 1; s < 4; ++s)
        if (av[s] > v1) { v1 = av[s]; w1 = l15 + (s << 4); }
      #pragma unroll
      for (int off = 1; off <= 8; off <<= 1) {
        float ov = __shfl_xor(v1, off); int ow = __shfl_xor(w1, off);
        if (ov > v1 || (ov == v1 && ow < w1)) { v1 = ov; w1 = ow; }
      }
      // one-hot row p: lane l15 owns cols 4*l15..+3 (64 lanes -> 1KB store)
      int w0 = l15 << 2;
      float4 vv;
      vv.x = (w1 == w0    ) ? 1.f : 0.f;
      vv.y = (w1 == w0 + 1) ? 1.f : 0.f;
      vv.z = (w1 == w0 + 2) ? 1.f : 0.f;
      vv.w = (w1 == w0 + 3) ? 1.f : 0.f;
      *(float4*)(out + (((size_t)(g * L_ + p)) << 6) + w0) = vv;
    }
  }
}

extern "C" void kernel_launch(void* const* d_in, const int* in_sizes, int n_in,
                              void* d_out, int out_size, void* d_ws, size_t ws_size,
                              hipStream_t stream) {
  const float* x = (const float*)d_in[0];
  float* out = (float*)d_out;
  float* cOut = out + ONEHOT_;
  char* ws = (char*)d_ws;
  float* c0n   = (float*)(ws);                     // 1 MiB [g][w][d]
  float* c2n   = (float*)(ws + (1u << 20));        // 1 MiB [g][w][d] final
  u64*  deltaI = (u64*)(ws + (3u << 20));          // 2 MiB [g][w][d] i64 fixed-point
  u64*  best   = (u64*)(ws + (5u << 20));          // 16 KiB [g][w] packed key||~p
  u32*  aPack  = (u32*)(ws + (5u << 20) + 65536);  // 512 KiB packed assignments

  // zero delta accumulators + best (0 == -inf sentinel under the key transform)
  hipMemsetAsync(ws + (3u << 20), 0, (2u << 20) + 16384, stream);

  hipLaunchKernelGGL(k1_sums,   dim3(2048), dim3(256),  0, stream, x, c0n);
  hipLaunchKernelGGL(k2_assign, dim3(512),  dim3(512),  0, stream, x, c0n, aPack, best);
  hipLaunchKernelGGL(k2d_delta, dim3(256),  dim3(1024), 0, stream, x, aPack, deltaI);
  hipLaunchKernelGGL(k3_final,  dim3(2048), dim3(128),  0, stream,
                     x, c0n, deltaI, best, cOut, c2n);
  hipLaunchKernelGGL(k4_onehot, dim3(512),  dim3(512),  0, stream, x, c2n, out);
}